// Round 1
// baseline (619.688 us; speedup 1.0000x reference)
//
#include <hip/hip_runtime.h>
#include <hip/hip_bf16.h>
#include <stdint.h>

typedef __bf16 bf16x8 __attribute__((ext_vector_type(8)));
typedef float f32x4 __attribute__((ext_vector_type(4)));

#define BM 128
#define BN 128
#define BK 32

// ---------------- conversion kernels ----------------

// x: f32 -> bf16 (RTNE), 8 elems/thread, grid-stride
__global__ void cvt_x_kernel(const float* __restrict__ in, __bf16* __restrict__ out,
                             size_t n8) {
    size_t i = (size_t)blockIdx.x * blockDim.x + threadIdx.x;
    size_t stride = (size_t)gridDim.x * blockDim.x;
    for (; i < n8; i += stride) {
        size_t base = i * 8;
        float4 f0 = *reinterpret_cast<const float4*>(in + base);
        float4 f1 = *reinterpret_cast<const float4*>(in + base + 4);
        bf16x8 o;
        o[0] = (__bf16)f0.x; o[1] = (__bf16)f0.y;
        o[2] = (__bf16)f0.z; o[3] = (__bf16)f0.w;
        o[4] = (__bf16)f1.x; o[5] = (__bf16)f1.y;
        o[6] = (__bf16)f1.z; o[7] = (__bf16)f1.w;
        *reinterpret_cast<bf16x8*>(out + base) = o;
    }
}

// w: f32 -> ternary {-1,0,1} in bf16 (exact).
// clip(sign(round(w)),-1,1) with round-half-even == (w>0.5 ? 1 : w<-0.5 ? -1 : 0)
// (at w==±0.5 exactly, rint gives ±0 -> 0; strict inequality matches)
__global__ void cvt_w_kernel(const float* __restrict__ in, __bf16* __restrict__ out,
                             size_t n8) {
    size_t i = (size_t)blockIdx.x * blockDim.x + threadIdx.x;
    size_t stride = (size_t)gridDim.x * blockDim.x;
    for (; i < n8; i += stride) {
        size_t base = i * 8;
        float4 f0 = *reinterpret_cast<const float4*>(in + base);
        float4 f1 = *reinterpret_cast<const float4*>(in + base + 4);
        float f[8] = {f0.x, f0.y, f0.z, f0.w, f1.x, f1.y, f1.z, f1.w};
        bf16x8 o;
#pragma unroll
        for (int j = 0; j < 8; ++j) {
            float t = (f[j] > 0.5f) ? 1.0f : ((f[j] < -0.5f) ? -1.0f : 0.0f);
            o[j] = (__bf16)t;
        }
        *reinterpret_cast<bf16x8*>(out + base) = o;
    }
}

// ---------------- main GEMM (m97 structure) ----------------
// A[M][K] bf16 (x), B[N][K] bf16 (ternary w), both K-major.
// C[M][N] f32 = A @ B^T + quantized bias.
// 128x128 tile, BK=32, 256 threads = 4 waves (2x2), each wave 64x64 = 4x4
// fragments of 16x16, mfma_f32_16x16x32_bf16.

__global__ __launch_bounds__(256) void gemm_kernel(
    const __bf16* __restrict__ A, const __bf16* __restrict__ B,
    const float* __restrict__ bias, float* __restrict__ out,
    int M, int N, int K) {
    __shared__ __bf16 sA[BM][BK];   // 8 KB
    __shared__ __bf16 sB[BN][BK];   // 8 KB

    const int t    = threadIdx.x;
    const int lane = t & 63;
    const int wave = t >> 6;
    const int wm   = (wave >> 1) * 64;   // wave row offset in tile
    const int wn   = (wave & 1) * 64;    // wave col offset in tile
    const int fr   = lane & 15;          // frag row (A:m, B:n, C:col)
    const int kg   = lane >> 4;          // K-group 0..3

    const int blockCol = blockIdx.x * BN;
    const int blockRow = blockIdx.y * BM;

    // staging: thread t loads 16B; row = t/4 (+64 for 2nd issue), col = (t&3)*8
    const int r4 = t >> 2;
    const int c8 = (t & 3) * 8;
    const __bf16* gA0 = A + (size_t)(blockRow + r4) * K + c8;
    const __bf16* gA1 = A + (size_t)(blockRow + 64 + r4) * K + c8;
    const __bf16* gB0 = B + (size_t)(blockCol + r4) * K + c8;
    const __bf16* gB1 = B + (size_t)(blockCol + 64 + r4) * K + c8;
    __bf16* lA0 = &sA[0][0] + (size_t)t * 8;      // byte off t*16, linear
    __bf16* lA1 = lA0 + 64 * BK;
    __bf16* lB0 = &sB[0][0] + (size_t)t * 8;
    __bf16* lB1 = lB0 + 64 * BK;

    f32x4 acc[4][4] = {};

    for (int k0 = 0; k0 < K; k0 += BK) {
        __builtin_amdgcn_global_load_lds(
            (const __attribute__((address_space(1))) void*)(gA0 + k0),
            (__attribute__((address_space(3))) void*)lA0, 16, 0, 0);
        __builtin_amdgcn_global_load_lds(
            (const __attribute__((address_space(1))) void*)(gA1 + k0),
            (__attribute__((address_space(3))) void*)lA1, 16, 0, 0);
        __builtin_amdgcn_global_load_lds(
            (const __attribute__((address_space(1))) void*)(gB0 + k0),
            (__attribute__((address_space(3))) void*)lB0, 16, 0, 0);
        __builtin_amdgcn_global_load_lds(
            (const __attribute__((address_space(1))) void*)(gB1 + k0),
            (__attribute__((address_space(3))) void*)lB1, 16, 0, 0);
        __syncthreads();   // drains vmcnt before barrier (compiler-inserted)

        bf16x8 av[4], bv[4];
#pragma unroll
        for (int i = 0; i < 4; ++i)
            av[i] = *reinterpret_cast<const bf16x8*>(&sA[wm + i * 16 + fr][kg * 8]);
#pragma unroll
        for (int j = 0; j < 4; ++j)
            bv[j] = *reinterpret_cast<const bf16x8*>(&sB[wn + j * 16 + fr][kg * 8]);

#pragma unroll
        for (int i = 0; i < 4; ++i)
#pragma unroll
            for (int j = 0; j < 4; ++j)
                acc[i][j] = __builtin_amdgcn_mfma_f32_16x16x32_bf16(
                    av[i], bv[j], acc[i][j], 0, 0, 0);
        __syncthreads();   // protect LDS before next stage overwrites
    }

    // epilogue: C/D layout col = lane&15, row = (lane>>4)*4 + r  [m89/m91]
#pragma unroll
    for (int j = 0; j < 4; ++j) {
        const int col = blockCol + wn + j * 16 + fr;
        const float bq = fminf(8.0f, fmaxf(-8.0f, rintf(bias[col])));
#pragma unroll
        for (int i = 0; i < 4; ++i) {
            const int row0 = blockRow + wm + i * 16 + kg * 4;
#pragma unroll
            for (int r = 0; r < 4; ++r) {
                out[(size_t)(row0 + r) * N + col] = acc[i][j][r] + bq;
            }
        }
    }
}

// ---------------- correctness fallback (ws too small) ----------------
__global__ void naive_kernel(const float* __restrict__ X, const float* __restrict__ W,
                             const float* __restrict__ bias, float* __restrict__ out,
                             int M, int N, int K) {
    int n = blockIdx.x * 16 + (threadIdx.x & 15);
    int m = blockIdx.y * 16 + (threadIdx.x >> 4);
    if (m >= M || n >= N) return;
    float acc = 0.f;
    for (int k = 0; k < K; ++k) {
        float w = W[(size_t)n * K + k];
        float t = (w > 0.5f) ? 1.0f : ((w < -0.5f) ? -1.0f : 0.0f);
        acc += X[(size_t)m * K + k] * t;
    }
    float b = fminf(8.0f, fmaxf(-8.0f, rintf(bias[n])));
    out[(size_t)m * N + n] = acc + b;
}

extern "C" void kernel_launch(void* const* d_in, const int* in_sizes, int n_in,
                              void* d_out, int out_size, void* d_ws, size_t ws_size,
                              hipStream_t stream) {
    const float* x    = (const float*)d_in[0];
    const float* w    = (const float*)d_in[1];
    const float* bias = (const float*)d_in[2];
    float* out        = (float*)d_out;

    const int N = in_sizes[2];            // 4096
    const int K = in_sizes[1] / N;        // 4096
    const int M = in_sizes[0] / K;        // 8192

    const size_t xb_elems = (size_t)M * K;
    const size_t wb_elems = (size_t)N * K;
    const size_t need = (xb_elems + wb_elems) * sizeof(__bf16);

    if (ws_size >= need && (M % BM == 0) && (N % BN == 0) && (K % BK == 0)) {
        __bf16* xb = (__bf16*)d_ws;
        __bf16* wb = xb + xb_elems;
        cvt_x_kernel<<<2048, 256, 0, stream>>>(x, xb, xb_elems / 8);
        cvt_w_kernel<<<1024, 256, 0, stream>>>(w, wb, wb_elems / 8);
        dim3 grid(N / BN, M / BM);
        gemm_kernel<<<grid, 256, 0, stream>>>(xb, wb, bias, out, M, N, K);
    } else {
        dim3 grid((N + 15) / 16, (M + 15) / 16);
        naive_kernel<<<grid, 256, 0, stream>>>(x, w, bias, out, M, N, K);
    }
}

// Round 2
// 497.326 us; speedup vs baseline: 1.2460x; 1.2460x over previous
//
#include <hip/hip_runtime.h>
#include <hip/hip_bf16.h>
#include <stdint.h>

typedef __bf16 bf16x8 __attribute__((ext_vector_type(8)));
typedef float f32x4 __attribute__((ext_vector_type(4)));

#define AS1 __attribute__((address_space(1)))
#define AS3 __attribute__((address_space(3)))

// ---------------- fused conversion kernel ----------------
// x: f32 -> bf16 (RTNE).  w: f32 -> ternary {-1,0,1} bf16 (exact).
__global__ void cvt_kernel(const float* __restrict__ x, const float* __restrict__ w,
                           __bf16* __restrict__ xb, __bf16* __restrict__ wb,
                           size_t nx8, size_t ntot8) {
    size_t i = (size_t)blockIdx.x * blockDim.x + threadIdx.x;
    size_t stride = (size_t)gridDim.x * blockDim.x;
    for (; i < ntot8; i += stride) {
        if (i < nx8) {
            size_t base = i * 8;
            float4 f0 = *reinterpret_cast<const float4*>(x + base);
            float4 f1 = *reinterpret_cast<const float4*>(x + base + 4);
            bf16x8 o;
            o[0] = (__bf16)f0.x; o[1] = (__bf16)f0.y; o[2] = (__bf16)f0.z; o[3] = (__bf16)f0.w;
            o[4] = (__bf16)f1.x; o[5] = (__bf16)f1.y; o[6] = (__bf16)f1.z; o[7] = (__bf16)f1.w;
            *reinterpret_cast<bf16x8*>(xb + base) = o;
        } else {
            size_t base = (i - nx8) * 8;
            float4 f0 = *reinterpret_cast<const float4*>(w + base);
            float4 f1 = *reinterpret_cast<const float4*>(w + base + 4);
            float f[8] = {f0.x, f0.y, f0.z, f0.w, f1.x, f1.y, f1.z, f1.w};
            bf16x8 o;
#pragma unroll
            for (int j = 0; j < 8; ++j) {
                float tv = (f[j] > 0.5f) ? 1.0f : ((f[j] < -0.5f) ? -1.0f : 0.0f);
                o[j] = (__bf16)tv;
            }
            *reinterpret_cast<bf16x8*>(wb + base) = o;
        }
    }
}

// ---------------- 256x256 8-phase GEMM ----------------
// A[M][K], B[N][K] bf16 (K-major). C = A @ B^T + quantized bias.
// 512 threads = 8 waves (2M x 4N). BK=64. LDS 128KB: [dbuf][A|B][256 slots][64] bf16.
// Slot permutation groups both waves' M-half (A) / N-half (B) rows into one
// 128-slot half-tile so staging never overwrites a region still to be read.
// Swizzle: phys_granule = logical_granule ^ (slot&7); linear gload_lds dest +
// pre-swizzled global source (rule 21).

#define GLOAD(srcp, dstoff) \
    __builtin_amdgcn_global_load_lds((const AS1 void*)(srcp), \
        (AS3 void*)(lds + (dstoff)), 16, 0, 0)

#define STAGE_A0(DB, KT) do { GLOAD(srcA00 + (size_t)(KT)*64, (DB)*65536 +     0 + t*16); \
                              GLOAD(srcA01 + (size_t)(KT)*64, (DB)*65536 +  8192 + t*16); } while(0)
#define STAGE_A1(DB, KT) do { GLOAD(srcA10 + (size_t)(KT)*64, (DB)*65536 + 16384 + t*16); \
                              GLOAD(srcA11 + (size_t)(KT)*64, (DB)*65536 + 24576 + t*16); } while(0)
#define STAGE_B0(DB, KT) do { GLOAD(srcB00 + (size_t)(KT)*64, (DB)*65536 + 32768 + t*16); \
                              GLOAD(srcB01 + (size_t)(KT)*64, (DB)*65536 + 40960 + t*16); } while(0)
#define STAGE_B1(DB, KT) do { GLOAD(srcB10 + (size_t)(KT)*64, (DB)*65536 + 49152 + t*16); \
                              GLOAD(srcB11 + (size_t)(KT)*64, (DB)*65536 + 57344 + t*16); } while(0)

#define LD8(off) (*(const bf16x8*)(lds + (off)))

#define PHASE_SYNC_PRE() do { asm volatile("" ::: "memory"); \
    __builtin_amdgcn_s_barrier(); \
    asm volatile("s_waitcnt lgkmcnt(0)" ::: "memory"); \
    __builtin_amdgcn_sched_barrier(0); } while(0)

#define PHASE_SYNC_POST() do { __builtin_amdgcn_sched_barrier(0); \
    asm volatile("" ::: "memory"); \
    __builtin_amdgcn_s_barrier(); \
    asm volatile("" ::: "memory"); } while(0)

#define MFMA_QUAD(I0, J0) do { \
    __builtin_amdgcn_s_setprio(1); \
    _Pragma("unroll") for (int kk2 = 0; kk2 < 2; ++kk2) \
    _Pragma("unroll") for (int ii2 = 0; ii2 < 4; ++ii2) \
    _Pragma("unroll") for (int jj2 = 0; jj2 < 2; ++jj2) \
        acc[(I0)+ii2][(J0)+jj2] = __builtin_amdgcn_mfma_f32_16x16x32_bf16( \
            af[ii2][kk2], bfr[(J0)+jj2][kk2], acc[(I0)+ii2][(J0)+jj2], 0, 0, 0); \
    __builtin_amdgcn_s_setprio(0); } while(0)

__global__ __launch_bounds__(512, 2) void gemm_kernel(
    const __bf16* __restrict__ A, const __bf16* __restrict__ B,
    const float* __restrict__ bias, float* __restrict__ out,
    int M, int N, int K) {
    __shared__ __align__(16) unsigned char lds[131072];

    const int t    = threadIdx.x;
    const int lane = t & 63;
    const int wave = t >> 6;
    const int wm   = wave >> 2;          // 0..1
    const int wn   = wave & 3;           // 0..3
    const int fr   = lane & 15;
    const int kg   = lane >> 4;          // 0..3
    const int NT   = K >> 6;             // K-tiles of 64

    // ---- XCD-aware block swizzle (bijective: nwg % 8 == 0 here) ----
    const int nwg  = gridDim.x * gridDim.y;
    int flat = blockIdx.y * gridDim.x + blockIdx.x;
    if ((nwg & 7) == 0) {
        const int cpx = nwg >> 3;
        flat = (flat & 7) * cpx + (flat >> 3);
    }
    const int blockCol = (flat % gridDim.x) * 256;
    const int blockRow = (flat / gridDim.x) * 256;

    // ---- staging source pointers (pre-swizzled rows/cols) ----
    const int tq  = t >> 3;                       // 0..63
    const int gce = ((t & 7) ^ (tq & 7)) * 8;     // swizzled col (elements)
    const __bf16* srcA00 = A + (size_t)(blockRow +   0 + tq) * K + gce;
    const __bf16* srcA01 = A + (size_t)(blockRow + 128 + tq) * K + gce;
    const __bf16* srcA10 = A + (size_t)(blockRow +  64 + tq) * K + gce;
    const __bf16* srcA11 = A + (size_t)(blockRow + 192 + tq) * K + gce;
    const int brB = (tq >> 5) * 64 + (tq & 31);
    const __bf16* srcB00 = B + (size_t)(blockCol +       brB) * K + gce;
    const __bf16* srcB01 = B + (size_t)(blockCol + 128 + brB) * K + gce;
    const __bf16* srcB10 = B + (size_t)(blockCol +  32 + brB) * K + gce;
    const __bf16* srcB11 = B + (size_t)(blockCol + 128 + 32 + brB) * K + gce;

    // ---- fragment read offsets (byte, within one dbuf) ----
    // A slot = (i>>2)*128 + wm*64 + (i&3)*16 + fr ; B slot = (j>>1)*128 + wn*32 + (j&1)*16 + fr
    int offA[8], offB[4];
#pragma unroll
    for (int i = 0; i < 8; ++i)
        offA[i] = (((i >> 2) * 128 + wm * 64 + (i & 3) * 16 + fr) << 7);
#pragma unroll
    for (int j = 0; j < 4; ++j)
        offB[j] = 32768 + ((((j >> 1) * 128 + wn * 32 + (j & 1) * 16 + fr)) << 7);
    const int sw0 = ((kg ^ (fr & 7)) << 4);   // kk=0 granule byte
    const int sw1 = sw0 ^ 64;                 // kk=1

    f32x4 acc[8][4] = {};
    bf16x8 af[4][2];
    bf16x8 bfr[4][2];

    // ---- prologue: K0 fully + K1 {B0, A0, B1} ----
    STAGE_A0(0, 0); STAGE_A1(0, 0); STAGE_B0(0, 0); STAGE_B1(0, 0);
    if (NT > 1) { STAGE_B0(1, 1); STAGE_A0(1, 1); STAGE_B1(1, 1); }
    if (NT > 1) { asm volatile("s_waitcnt vmcnt(6)" ::: "memory"); }
    else        { asm volatile("s_waitcnt vmcnt(0)" ::: "memory"); }
    __builtin_amdgcn_s_barrier();
    asm volatile("" ::: "memory");

    for (int kt = 0; kt < NT; ++kt) {
        const int db  = kt & 1;
        const int dbB = db << 16;
        const bool pf1 = (kt + 1 < NT);
        const bool pf2 = (kt + 2 < NT);

        // ---- phase 1: quadrant (M0, N01) ----
#pragma unroll
        for (int ii = 0; ii < 4; ++ii) {
            af[ii][0] = LD8(dbB + offA[ii] + sw0);
            af[ii][1] = LD8(dbB + offA[ii] + sw1);
        }
#pragma unroll
        for (int jj = 0; jj < 2; ++jj) {
            bfr[jj][0] = LD8(dbB + offB[jj] + sw0);
            bfr[jj][1] = LD8(dbB + offB[jj] + sw1);
        }
        if (pf1) STAGE_A1(db ^ 1, kt + 1);
        PHASE_SYNC_PRE();
        MFMA_QUAD(0, 0);
        PHASE_SYNC_POST();

        // ---- phase 2: quadrant (M0, N23) ----
#pragma unroll
        for (int jj = 2; jj < 4; ++jj) {
            bfr[jj][0] = LD8(dbB + offB[jj] + sw0);
            bfr[jj][1] = LD8(dbB + offB[jj] + sw1);
        }
        if (pf2) STAGE_B0(db, kt + 2);
        PHASE_SYNC_PRE();
        MFMA_QUAD(0, 2);
        PHASE_SYNC_POST();

        // ---- phase 3: quadrant (M1, N23) ----
#pragma unroll
        for (int ii = 0; ii < 4; ++ii) {
            af[ii][0] = LD8(dbB + offA[ii + 4] + sw0);
            af[ii][1] = LD8(dbB + offA[ii + 4] + sw1);
        }
        if (pf2) STAGE_A0(db, kt + 2);
        PHASE_SYNC_PRE();
        MFMA_QUAD(4, 2);
        PHASE_SYNC_POST();

        // ---- phase 4: quadrant (M1, N01) ----
        if (pf2) STAGE_B1(db, kt + 2);
        if (pf2)      { asm volatile("s_waitcnt vmcnt(6)" ::: "memory"); }
        else if (pf1) { asm volatile("s_waitcnt vmcnt(0)" ::: "memory"); }
        PHASE_SYNC_PRE();
        MFMA_QUAD(4, 0);
        PHASE_SYNC_POST();
    }

    // ---- epilogue: C/D layout col = lane&15, row = (lane>>4)*4 + r ----
#pragma unroll
    for (int j = 0; j < 4; ++j) {
        const int col = blockCol + wn * 64 + j * 16 + fr;
        const float bq = fminf(8.0f, fmaxf(-8.0f, rintf(bias[col])));
#pragma unroll
        for (int i = 0; i < 8; ++i) {
            const int row0 = blockRow + wm * 128 + i * 16 + kg * 4;
#pragma unroll
            for (int r = 0; r < 4; ++r)
                out[(size_t)(row0 + r) * N + col] = acc[i][j][r] + bq;
        }
    }
}

// ---------------- correctness fallback ----------------
__global__ void naive_kernel(const float* __restrict__ X, const float* __restrict__ W,
                             const float* __restrict__ bias, float* __restrict__ out,
                             int M, int N, int K) {
    int n = blockIdx.x * 16 + (threadIdx.x & 15);
    int m = blockIdx.y * 16 + (threadIdx.x >> 4);
    if (m >= M || n >= N) return;
    float acc = 0.f;
    for (int k = 0; k < K; ++k) {
        float w = W[(size_t)n * K + k];
        float tv = (w > 0.5f) ? 1.0f : ((w < -0.5f) ? -1.0f : 0.0f);
        acc += X[(size_t)m * K + k] * tv;
    }
    float b = fminf(8.0f, fmaxf(-8.0f, rintf(bias[n])));
    out[(size_t)m * N + n] = acc + b;
}

extern "C" void kernel_launch(void* const* d_in, const int* in_sizes, int n_in,
                              void* d_out, int out_size, void* d_ws, size_t ws_size,
                              hipStream_t stream) {
    const float* x    = (const float*)d_in[0];
    const float* w    = (const float*)d_in[1];
    const float* bias = (const float*)d_in[2];
    float* out        = (float*)d_out;

    const int N = in_sizes[2];            // 4096
    const int K = in_sizes[1] / N;        // 4096
    const int M = in_sizes[0] / K;        // 8192

    const size_t xb_elems = (size_t)M * K;
    const size_t wb_elems = (size_t)N * K;
    const size_t need = (xb_elems + wb_elems) * sizeof(__bf16);

    if (ws_size >= need && (M % 256 == 0) && (N % 256 == 0) && (K % 64 == 0) && K >= 192) {
        __bf16* xb = (__bf16*)d_ws;
        __bf16* wb = xb + xb_elems;
        cvt_kernel<<<4096, 256, 0, stream>>>(x, w, xb, wb, xb_elems / 8,
                                             (xb_elems + wb_elems) / 8);
        dim3 grid(N / 256, M / 256);
        gemm_kernel<<<grid, 512, 0, stream>>>(xb, wb, bias, out, M, N, K);
    } else {
        dim3 grid((N + 15) / 16, (M + 15) / 16);
        naive_kernel<<<grid, 256, 0, stream>>>(x, w, bias, out, M, N, K);
    }
}

// Round 3
// 496.332 us; speedup vs baseline: 1.2485x; 1.0020x over previous
//
#include <hip/hip_runtime.h>
#include <hip/hip_bf16.h>
#include <stdint.h>

typedef __bf16 bf16x8 __attribute__((ext_vector_type(8)));
typedef __bf16 bf16x4 __attribute__((ext_vector_type(4)));
typedef float f32x4 __attribute__((ext_vector_type(4)));

#define AS1 __attribute__((address_space(1)))
#define AS3 __attribute__((address_space(3)))

// ---------------- fused conversion kernel ----------------
// Lane-contiguous float4 loads (16B/lane), bf16x4 stores (8B/lane).
// x: f32 -> bf16 (RTNE).  w: f32 -> ternary {-1,0,1} bf16 (exact).
__global__ void cvt_kernel(const float* __restrict__ x, const float* __restrict__ w,
                           __bf16* __restrict__ xb, __bf16* __restrict__ wb,
                           size_t nx4, size_t nw4) {
    const size_t tid = (size_t)blockIdx.x * blockDim.x + threadIdx.x;
    const size_t stride = (size_t)gridDim.x * blockDim.x;
    const float4* __restrict__ x4 = (const float4*)x;
    const float4* __restrict__ w4 = (const float4*)w;
    bf16x4* __restrict__ xb4 = (bf16x4*)xb;
    bf16x4* __restrict__ wb4 = (bf16x4*)wb;
    for (size_t i = tid; i < nx4; i += stride) {
        float4 f = x4[i];
        bf16x4 o;
        o[0] = (__bf16)f.x; o[1] = (__bf16)f.y; o[2] = (__bf16)f.z; o[3] = (__bf16)f.w;
        xb4[i] = o;
    }
    for (size_t i = tid; i < nw4; i += stride) {
        float4 f = w4[i];
        float g[4] = {f.x, f.y, f.z, f.w};
        bf16x4 o;
#pragma unroll
        for (int j = 0; j < 4; ++j) {
            float tv = (g[j] > 0.5f) ? 1.0f : ((g[j] < -0.5f) ? -1.0f : 0.0f);
            o[j] = (__bf16)tv;
        }
        wb4[i] = o;
    }
}

// ---------------- 256x256 8-phase GEMM ----------------
// A[M][K], B[N][K] bf16 (K-major). C = A @ B^T + quantized bias.
// 512 threads = 8 waves (2M x 4N). BK=64. LDS 128KB dbuf.
// Swizzle: LDS granule g of slot s holds global granule g ^ (s&7);
// linear gload_lds dest + pre-swizzled global source (rule 21).
// B-fragments for tile kt+1 are read in tile kt's phase-4 MFMA shadow
// (after vmcnt(6) guarantees kt+1 landed) -> read balance 8/0/8/0.

#define GLOAD(srcp, dstoff) \
    __builtin_amdgcn_global_load_lds((const AS1 void*)(srcp), \
        (AS3 void*)(lds + (dstoff)), 16, 0, 0)

#define STAGE_A0(DB, KT) do { GLOAD(srcA00 + (size_t)(KT)*64, (DB)*65536 +     0 + t*16); \
                              GLOAD(srcA01 + (size_t)(KT)*64, (DB)*65536 +  8192 + t*16); } while(0)
#define STAGE_A1(DB, KT) do { GLOAD(srcA10 + (size_t)(KT)*64, (DB)*65536 + 16384 + t*16); \
                              GLOAD(srcA11 + (size_t)(KT)*64, (DB)*65536 + 24576 + t*16); } while(0)
#define STAGE_B0(DB, KT) do { GLOAD(srcB00 + (size_t)(KT)*64, (DB)*65536 + 32768 + t*16); \
                              GLOAD(srcB01 + (size_t)(KT)*64, (DB)*65536 + 40960 + t*16); } while(0)
#define STAGE_B1(DB, KT) do { GLOAD(srcB10 + (size_t)(KT)*64, (DB)*65536 + 49152 + t*16); \
                              GLOAD(srcB11 + (size_t)(KT)*64, (DB)*65536 + 57344 + t*16); } while(0)

#define LD8(off) (*(const bf16x8*)(lds + (off)))

#define PHASE_SYNC_PRE() do { asm volatile("" ::: "memory"); \
    __builtin_amdgcn_s_barrier(); \
    asm volatile("s_waitcnt lgkmcnt(0)" ::: "memory"); \
    __builtin_amdgcn_sched_barrier(0); } while(0)

#define PHASE_SYNC_POST() do { __builtin_amdgcn_sched_barrier(0); \
    asm volatile("" ::: "memory"); \
    __builtin_amdgcn_s_barrier(); \
    asm volatile("" ::: "memory"); } while(0)

#define MFMA_QUAD(I0, J0) do { \
    __builtin_amdgcn_s_setprio(1); \
    _Pragma("unroll") for (int kk2 = 0; kk2 < 2; ++kk2) \
    _Pragma("unroll") for (int ii2 = 0; ii2 < 4; ++ii2) \
    _Pragma("unroll") for (int jj2 = 0; jj2 < 2; ++jj2) \
        acc[(I0)+ii2][(J0)+jj2] = __builtin_amdgcn_mfma_f32_16x16x32_bf16( \
            af[ii2][kk2], bfr[(J0)+jj2][kk2], acc[(I0)+ii2][(J0)+jj2], 0, 0, 0); \
    __builtin_amdgcn_s_setprio(0); } while(0)

__global__ __launch_bounds__(512, 2) void gemm_kernel(
    const __bf16* __restrict__ A, const __bf16* __restrict__ B,
    const float* __restrict__ bias, float* __restrict__ out,
    int M, int N, int K) {
    __shared__ __align__(16) unsigned char lds[131072];

    const int t    = threadIdx.x;
    const int lane = t & 63;
    const int wave = t >> 6;
    const int wm   = wave >> 2;          // 0..1
    const int wn   = wave & 3;           // 0..3
    const int fr   = lane & 15;
    const int kg   = lane >> 4;          // 0..3
    const int NT   = K >> 6;             // K-tiles of 64

    // ---- XCD-aware block swizzle (bijective: nwg % 8 == 0 here) ----
    const int nwg  = gridDim.x * gridDim.y;
    int flat = blockIdx.y * gridDim.x + blockIdx.x;
    if ((nwg & 7) == 0) {
        const int cpx = nwg >> 3;
        flat = (flat & 7) * cpx + (flat >> 3);
    }
    const int blockCol = (flat % gridDim.x) * 256;
    const int blockRow = (flat / gridDim.x) * 256;

    // ---- staging source pointers (pre-swizzled cols) ----
    const int tq  = t >> 3;                       // 0..63
    const int gce = ((t & 7) ^ (tq & 7)) * 8;     // swizzled col (elements)
    const __bf16* srcA00 = A + (size_t)(blockRow +   0 + tq) * K + gce;
    const __bf16* srcA01 = A + (size_t)(blockRow + 128 + tq) * K + gce;
    const __bf16* srcA10 = A + (size_t)(blockRow +  64 + tq) * K + gce;
    const __bf16* srcA11 = A + (size_t)(blockRow + 192 + tq) * K + gce;
    const int brB = (tq >> 5) * 64 + (tq & 31);
    const __bf16* srcB00 = B + (size_t)(blockCol +       brB) * K + gce;
    const __bf16* srcB01 = B + (size_t)(blockCol + 128 + brB) * K + gce;
    const __bf16* srcB10 = B + (size_t)(blockCol +  32 + brB) * K + gce;
    const __bf16* srcB11 = B + (size_t)(blockCol + 128 + 32 + brB) * K + gce;

    // ---- fragment read offsets (byte, within one dbuf) ----
    int offA[8], offB[4];
#pragma unroll
    for (int i = 0; i < 8; ++i)
        offA[i] = (((i >> 2) * 128 + wm * 64 + (i & 3) * 16 + fr) << 7);
#pragma unroll
    for (int j = 0; j < 4; ++j)
        offB[j] = 32768 + ((((j >> 1) * 128 + wn * 32 + (j & 1) * 16 + fr)) << 7);
    const int sw0 = ((kg ^ (fr & 7)) << 4);   // kk=0 granule byte
    const int sw1 = sw0 ^ 64;                 // kk=1

    f32x4 acc[8][4] = {};
    bf16x8 af[4][2];
    bf16x8 bfr[4][2];

    // ---- prologue: K0 fully + K1 {B0, A0, B1}; then preload K0's B frags ----
    STAGE_A0(0, 0); STAGE_A1(0, 0); STAGE_B0(0, 0); STAGE_B1(0, 0);
    if (NT > 1) { STAGE_B0(1, 1); STAGE_A0(1, 1); STAGE_B1(1, 1); }
    if (NT > 1) { asm volatile("s_waitcnt vmcnt(6)" ::: "memory"); }
    else        { asm volatile("s_waitcnt vmcnt(0)" ::: "memory"); }
    __builtin_amdgcn_s_barrier();
    asm volatile("" ::: "memory");
#pragma unroll
    for (int jj = 0; jj < 4; ++jj) {
        bfr[jj][0] = LD8(offB[jj] + sw0);
        bfr[jj][1] = LD8(offB[jj] + sw1);
    }

    for (int kt = 0; kt < NT; ++kt) {
        const int db  = kt & 1;
        const int dbB = db << 16;
        const bool pf1 = (kt + 1 < NT);
        const bool pf2 = (kt + 2 < NT);

        // ---- phase 1: (M0, N01). reads: af <- A0 ----
#pragma unroll
        for (int ii = 0; ii < 4; ++ii) {
            af[ii][0] = LD8(dbB + offA[ii] + sw0);
            af[ii][1] = LD8(dbB + offA[ii] + sw1);
        }
        if (pf1) STAGE_A1(db ^ 1, kt + 1);
        PHASE_SYNC_PRE();
        MFMA_QUAD(0, 0);
        PHASE_SYNC_POST();

        // ---- phase 2: (M0, N23). no reads (bfr23 preloaded) ----
        if (pf2) STAGE_B0(db, kt + 2);
        PHASE_SYNC_PRE();
        MFMA_QUAD(0, 2);
        PHASE_SYNC_POST();

        // ---- phase 3: (M1, N23). reads: af <- A1 ----
#pragma unroll
        for (int ii = 0; ii < 4; ++ii) {
            af[ii][0] = LD8(dbB + offA[ii + 4] + sw0);
            af[ii][1] = LD8(dbB + offA[ii + 4] + sw1);
        }
        if (pf2) STAGE_A0(db, kt + 2);
        PHASE_SYNC_PRE();
        MFMA_QUAD(4, 2);
        PHASE_SYNC_POST();

        // ---- phase 4: (M1, N01). B frags of kt+1 read in MFMA shadow ----
        if (pf2) STAGE_B1(db, kt + 2);
        if (pf2)      { asm volatile("s_waitcnt vmcnt(6)" ::: "memory"); }
        else if (pf1) { asm volatile("s_waitcnt vmcnt(0)" ::: "memory"); }
        PHASE_SYNC_PRE();
        MFMA_QUAD(4, 0);
        {
            const int nb = dbB ^ 65536;   // next tile's buffer
#pragma unroll
            for (int jj = 0; jj < 4; ++jj) {
                bfr[jj][0] = LD8(nb + offB[jj] + sw0);
                bfr[jj][1] = LD8(nb + offB[jj] + sw1);
            }
        }
        PHASE_SYNC_POST();
    }

    // ---- epilogue: C/D layout col = lane&15, row = (lane>>4)*4 + r ----
#pragma unroll
    for (int j = 0; j < 4; ++j) {
        const int col = blockCol + wn * 64 + j * 16 + fr;
        const float bq = fminf(8.0f, fmaxf(-8.0f, rintf(bias[col])));
#pragma unroll
        for (int i = 0; i < 8; ++i) {
            const int row0 = blockRow + wm * 128 + i * 16 + kg * 4;
#pragma unroll
            for (int r = 0; r < 4; ++r)
                out[(size_t)(row0 + r) * N + col] = acc[i][j][r] + bq;
        }
    }
}

// ---------------- correctness fallback ----------------
__global__ void naive_kernel(const float* __restrict__ X, const float* __restrict__ W,
                             const float* __restrict__ bias, float* __restrict__ out,
                             int M, int N, int K) {
    int n = blockIdx.x * 16 + (threadIdx.x & 15);
    int m = blockIdx.y * 16 + (threadIdx.x >> 4);
    if (m >= M || n >= N) return;
    float acc = 0.f;
    for (int k = 0; k < K; ++k) {
        float w = W[(size_t)n * K + k];
        float tv = (w > 0.5f) ? 1.0f : ((w < -0.5f) ? -1.0f : 0.0f);
        acc += X[(size_t)m * K + k] * tv;
    }
    float b = fminf(8.0f, fmaxf(-8.0f, rintf(bias[n])));
    out[(size_t)m * N + n] = acc + b;
}

extern "C" void kernel_launch(void* const* d_in, const int* in_sizes, int n_in,
                              void* d_out, int out_size, void* d_ws, size_t ws_size,
                              hipStream_t stream) {
    const float* x    = (const float*)d_in[0];
    const float* w    = (const float*)d_in[1];
    const float* bias = (const float*)d_in[2];
    float* out        = (float*)d_out;

    const int N = in_sizes[2];            // 4096
    const int K = in_sizes[1] / N;        // 4096
    const int M = in_sizes[0] / K;        // 8192

    const size_t xb_elems = (size_t)M * K;
    const size_t wb_elems = (size_t)N * K;
    const size_t need = (xb_elems + wb_elems) * sizeof(__bf16);

    if (ws_size >= need && (M % 256 == 0) && (N % 256 == 0) && (K % 64 == 0) && K >= 192) {
        __bf16* xb = (__bf16*)d_ws;
        __bf16* wb = xb + xb_elems;
        cvt_kernel<<<2048, 256, 0, stream>>>(x, w, xb, wb, xb_elems / 4, wb_elems / 4);
        dim3 grid(N / 256, M / 256);
        gemm_kernel<<<grid, 512, 0, stream>>>(xb, wb, bias, out, M, N, K);
    } else {
        dim3 grid((N + 15) / 16, (M + 15) / 16);
        naive_kernel<<<grid, 256, 0, stream>>>(x, w, bias, out, M, N, K);
    }
}